// Round 3
// baseline (4009.748 us; speedup 1.0000x reference)
//
#include <hip/hip_runtime.h>

#define HW   4096
#define Hh   64
#define Ww   64
#define NB   27
#define EPSBN 1e-5f

struct ConvJob {
    const float* in;
    const float* w;
    const float* b;
    const float* g;
    const float* be;
    const float* m;
    const float* v;
    float*       out;
    int Cin;
    int Ochan;
    int relu;
};

// ---------------------------------------------------------------------------
// Fused multi-job 1x1-conv (+optional BN+ReLU) GEMM, fp32.
// blockIdx.y selects the job (block-uniform). Tile: 32 outputs x 256 pixels.
// Block = (64 px lanes, 4 o-groups); each thread 8 outputs x 4 pixels.
// Weights double-buffered in LDS (one barrier per 64-ch chunk); x prefetched
// one c4-step ahead in registers so global loads overlap the 128-FMA body.
// ---------------------------------------------------------------------------
__global__ __launch_bounds__(256, 5)
void conv1x1_fused(ConvJob J0, ConvJob J1, ConvJob J2, int n0, int n01)
{
    __shared__ float wlds[2][32][68];           // +4 pad: stage writes 2-way (free)
    const int tx = threadIdx.x;                 // 0..63 pixel lanes
    const int ty = threadIdx.y;                 // 0..3 output groups
    const int b  = blockIdx.z;

    const int by   = blockIdx.y;
    const bool in0 = by < n0;
    const bool in1 = !in0 && by < n01;
    const ConvJob& J = in0 ? J0 : (in1 ? J1 : J2);
    const int ob    = by - (in0 ? 0 : (in1 ? n0 : n01));
    const int obase = ob * 32;
    const int Cin   = J.Cin;

    const float* inb = J.in + (size_t)b * Cin * HW;
    const int p0 = blockIdx.x * 256 + tx * 4;

    float acc[8][4];
    #pragma unroll
    for (int j = 0; j < 8; ++j)
        #pragma unroll
        for (int k = 0; k < 4; ++k) acc[j][k] = 0.f;

    const int tid  = ty * 64 + tx;
    const int wrow = tid >> 3;                  // 0..31
    const int wcol = (tid & 7) * 8;             // 0..56
    const float* wbase = J.w + (size_t)(obase + wrow) * Cin + wcol;

    // stage chunk 0 weights into buf 0
    *(float4*)&wlds[0][wrow][wcol]     = *(const float4*)wbase;
    *(float4*)&wlds[0][wrow][wcol + 4] = *(const float4*)(wbase + 4);

    // prefetch first x block (channels 0..3)
    const float* xpf = inb + p0;
    float4 nx0 = *(const float4*)(xpf);
    float4 nx1 = *(const float4*)(xpf + HW);
    float4 nx2 = *(const float4*)(xpf + 2 * HW);
    float4 nx3 = *(const float4*)(xpf + 3 * HW);
    xpf += 4 * HW;

    __syncthreads();

    const int nchunks = Cin >> 6;
    for (int ch = 0; ch < nchunks; ++ch) {
        const int cur = ch & 1;
        if (ch + 1 < nchunks) {                 // stage next chunk (no barrier)
            const float* ws2 = wbase + (ch + 1) * 64;
            *(float4*)&wlds[cur ^ 1][wrow][wcol]     = *(const float4*)ws2;
            *(float4*)&wlds[cur ^ 1][wrow][wcol + 4] = *(const float4*)(ws2 + 4);
        }
        #pragma unroll 4
        for (int c4 = 0; c4 < 64; c4 += 4) {
            const float4 x0 = nx0, x1 = nx1, x2 = nx2, x3 = nx3;
            if (ch * 64 + c4 + 4 < Cin) {       // uniform; false only at the very end
                nx0 = *(const float4*)(xpf);
                nx1 = *(const float4*)(xpf + HW);
                nx2 = *(const float4*)(xpf + 2 * HW);
                nx3 = *(const float4*)(xpf + 3 * HW);
                xpf += 4 * HW;
            }
            #pragma unroll
            for (int j = 0; j < 8; ++j) {
                const float4 wv = *(const float4*)&wlds[cur][ty * 8 + j][c4];
                acc[j][0] = fmaf(wv.w, x3.x, fmaf(wv.z, x2.x, fmaf(wv.y, x1.x, fmaf(wv.x, x0.x, acc[j][0]))));
                acc[j][1] = fmaf(wv.w, x3.y, fmaf(wv.z, x2.y, fmaf(wv.y, x1.y, fmaf(wv.x, x0.y, acc[j][1]))));
                acc[j][2] = fmaf(wv.w, x3.z, fmaf(wv.z, x2.z, fmaf(wv.y, x1.z, fmaf(wv.x, x0.z, acc[j][2]))));
                acc[j][3] = fmaf(wv.w, x3.w, fmaf(wv.z, x2.w, fmaf(wv.y, x1.w, fmaf(wv.x, x0.w, acc[j][3]))));
            }
        }
        __syncthreads();
    }

    #pragma unroll
    for (int j = 0; j < 8; ++j) {
        const int o = obase + ty * 8 + j;
        float s, off;
        if (J.g != nullptr) {
            s   = J.g[o] * rsqrtf(J.v[o] + EPSBN);
            off = fmaf(J.b[o] - J.m[o], s, J.be[o]);   // b*s + be - m*s
        } else {
            s   = 1.f;
            off = J.b[o];
        }
        float r0 = fmaf(acc[j][0], s, off);
        float r1 = fmaf(acc[j][1], s, off);
        float r2 = fmaf(acc[j][2], s, off);
        float r3 = fmaf(acc[j][3], s, off);
        if (J.relu) {
            r0 = fmaxf(r0, 0.f); r1 = fmaxf(r1, 0.f);
            r2 = fmaxf(r2, 0.f); r3 = fmaxf(r3, 0.f);
        }
        *(float4*)(J.out + ((size_t)b * J.Ochan + o) * HW + p0) = make_float4(r0, r1, r2, r3);
    }
}

// ---------------------------------------------------------------------------
// Attention, branch-free (round-1 version): clamped indices, arithmetic
// zeroing of OOB neighbors, LDS cross-wave sim reduction.
// ---------------------------------------------------------------------------
__global__ __launch_bounds__(256)
void attn_kernel(const float* __restrict__ key, const float* __restrict__ qry,
                 const float* __restrict__ val, float* __restrict__ ctx)
{
    __shared__ float psim[4][NB][64];
    const int tx = threadIdx.x;
    const int ty = threadIdx.y;
    const int b  = blockIdx.y;
    const int p  = blockIdx.x * 64 + tx;
    const int y  = p >> 6;
    const int xc = p & 63;
    const size_t bo = (size_t)b * 256 * HW;
    const float* kb = key + bo;
    const float* qb = qry + bo;
    const float* vb = val + bo;

    int   idx[NB];
    float valf[NB];
    #pragma unroll
    for (int n = 0; n < NB; ++n) {
        const int d  = (n < 9) ? 1 : (n < 18 ? 2 : 4);
        const int i  = (n / 3) % 3 - 1;
        const int j  = n % 3 - 1;
        const int yy = y + i * d, xx = xc + j * d;
        const bool ok = ((unsigned)yy < (unsigned)Hh) && ((unsigned)xx < (unsigned)Ww);
        const int yyc = min(max(yy, 0), Hh - 1);
        const int xxc = min(max(xx, 0), Ww - 1);
        idx[n]  = yyc * Ww + xxc;
        valf[n] = ok ? 1.f : 0.f;
    }

    float sim[NB];
    #pragma unroll
    for (int n = 0; n < NB; ++n) sim[n] = 0.f;

    const int c0 = ty * 64;
    #pragma unroll 2
    for (int c = c0; c < c0 + 64; ++c) {
        const float  qv = qb[(size_t)c * HW + p];
        const float* kc = kb + (size_t)c * HW;
        #pragma unroll
        for (int n = 0; n < NB; ++n)
            sim[n] = fmaf(kc[idx[n]], qv, sim[n]);
    }

    #pragma unroll
    for (int n = 0; n < NB; ++n) psim[ty][n][tx] = sim[n] * valf[n];
    __syncthreads();
    #pragma unroll
    for (int n = 0; n < NB; ++n)
        sim[n] = (psim[0][n][tx] + psim[1][n][tx]) + (psim[2][n][tx] + psim[3][n][tx]);

    float mx = sim[0];
    #pragma unroll
    for (int n = 1; n < NB; ++n) mx = fmaxf(mx, sim[n]);
    float sum = 0.f;
    #pragma unroll
    for (int n = 0; n < NB; ++n) { sim[n] = __expf(sim[n] - mx); sum += sim[n]; }
    const float inv = 1.f / sum;
    #pragma unroll
    for (int n = 0; n < NB; ++n) sim[n] = sim[n] * inv * valf[n];

    #pragma unroll 2
    for (int c = c0; c < c0 + 64; ++c) {
        const float* vc = vb + (size_t)c * HW;
        float a = 0.f;
        #pragma unroll
        for (int n = 0; n < NB; ++n)
            a = fmaf(sim[n], vc[idx[n]], a);
        ctx[bo + (size_t)c * HW + p] = a;
    }
}

extern "C" void kernel_launch(void* const* d_in, const int* in_sizes, int n_in,
                              void* d_out, int out_size, void* d_ws, size_t ws_size,
                              hipStream_t stream)
{
    (void)in_sizes; (void)n_in; (void)out_size; (void)ws_size;
    const float* x     = (const float*)d_in[0];
    const float* k1_w  = (const float*)d_in[1];
    const float* k1_b  = (const float*)d_in[2];
    const float* k1_g  = (const float*)d_in[3];
    const float* k1_be = (const float*)d_in[4];
    const float* k1_m  = (const float*)d_in[5];
    const float* k1_v  = (const float*)d_in[6];
    const float* k2_w  = (const float*)d_in[7];
    const float* k2_b  = (const float*)d_in[8];
    const float* k2_g  = (const float*)d_in[9];
    const float* k2_be = (const float*)d_in[10];
    const float* k2_m  = (const float*)d_in[11];
    const float* k2_v  = (const float*)d_in[12];
    const float* q1_w  = (const float*)d_in[13];
    const float* q1_b  = (const float*)d_in[14];
    const float* q1_g  = (const float*)d_in[15];
    const float* q1_be = (const float*)d_in[16];
    const float* q1_m  = (const float*)d_in[17];
    const float* q1_v  = (const float*)d_in[18];
    const float* q2_w  = (const float*)d_in[19];
    const float* q2_b  = (const float*)d_in[20];
    const float* q2_g  = (const float*)d_in[21];
    const float* q2_be = (const float*)d_in[22];
    const float* q2_m  = (const float*)d_in[23];
    const float* q2_v  = (const float*)d_in[24];
    const float* v_w   = (const float*)d_in[25];
    const float* v_b   = (const float*)d_in[26];
    const float* w_w   = (const float*)d_in[27];
    const float* w_b   = (const float*)d_in[28];

    float* ws = (float*)d_ws;
    const size_t S = (size_t)4 * 256 * HW;
    float* v_buf   = ws;
    float* k1_buf  = ws + S;
    float* q1_buf  = ws + 2 * S;
    float* key_buf = ws + 3 * S;
    float* qry_buf = ws + 4 * S;
    float* ctx_buf = k1_buf;                    // k1 dead after stage 2 -> reuse

    const dim3 blk(64, 4);

    ConvJob jv  = { x,      v_w,  v_b,  nullptr, nullptr, nullptr, nullptr, v_buf,          512, 256, 0 };
    ConvJob jk1 = { x,      k1_w, k1_b, k1_g,    k1_be,   k1_m,    k1_v,    k1_buf,         512, 256, 1 };
    ConvJob jq1 = { x,      q1_w, q1_b, q1_g,    q1_be,   q1_m,    q1_v,    q1_buf,         512, 256, 1 };
    ConvJob jk2 = { k1_buf, k2_w, k2_b, k2_g,    k2_be,   k2_m,    k2_v,    key_buf,        256, 256, 1 };
    ConvJob jq2 = { q1_buf, q2_w, q2_b, q2_g,    q2_be,   q2_m,    q2_v,    qry_buf,        256, 256, 1 };
    ConvJob jw  = { ctx_buf, w_w, w_b,  nullptr, nullptr, nullptr, nullptr, (float*)d_out,  256, 512, 0 };

    // stage 1: v | k1 | q1 fused (each 8 o-blocks) -> 1536 blocks
    conv1x1_fused<<<dim3(16, 24, 4), blk, 0, stream>>>(jv, jk1, jq1, 8, 16);
    // stage 2: k2 | q2 fused -> 1024 blocks
    conv1x1_fused<<<dim3(16, 16, 4), blk, 0, stream>>>(jk2, jq2, jq2, 8, 16);
    // stage 3: attention
    attn_kernel<<<dim3(64, 4), blk, 0, stream>>>(key_buf, qry_buf, v_buf, ctx_buf);
    // stage 4: final conv (256 -> 512), 16 o-blocks -> 1024 blocks
    conv1x1_fused<<<dim3(16, 16, 4), blk, 0, stream>>>(jw, jw, jw, 16, 16);
}

// Round 4
// 368.369 us; speedup vs baseline: 10.8851x; 10.8851x over previous
//
#include <hip/hip_runtime.h>

#define HW   4096
#define Hh   64
#define Ww   64
#define NB   27
#define EPSBN 1e-5f

struct ConvJob {
    const float* in;
    const float* w;
    const float* b;
    const float* g;
    const float* be;
    const float* m;
    const float* v;
    float*       out;
    int Cin;
    int Ochan;
    int relu;
};

// ---------------------------------------------------------------------------
// Fused multi-job 1x1-conv (+optional BN+ReLU) GEMM, fp32.
// blockIdx.y selects the job. IMPORTANT: job fields are selected one-by-one
// with block-uniform ternaries on VALUES (s_cselect in SGPRs). Taking a
// reference to a runtime-selected struct (round-3 bug) forced everything to
// scratch: 7.2 GB/dispatch of spill writes, 4x slowdown.
// Tile: 32 outputs x 256 pixels; block (64 px lanes, 4 o-groups);
// 8 outputs x 4 pixels per thread. Weights double-buffered in LDS (one
// barrier per 64-ch chunk); x prefetched one c4-step ahead in registers.
// ---------------------------------------------------------------------------
__global__ __launch_bounds__(256)
void conv1x1_fused(ConvJob J0, ConvJob J1, ConvJob J2, int n0, int n01)
{
    __shared__ float wlds[2][32][68];
    const int tx = threadIdx.x;                 // 0..63 pixel lanes
    const int ty = threadIdx.y;                 // 0..3 output groups
    const int b  = blockIdx.z;

    const int by   = blockIdx.y;
    const bool in0 = by < n0;
    const bool in1 = !in0 && by < n01;
#define SELJ(f) (in0 ? J0.f : (in1 ? J1.f : J2.f))
    const float* Jin  = SELJ(in);
    const float* Jw   = SELJ(w);
    const float* Jb   = SELJ(b);
    const float* Jg   = SELJ(g);
    const float* Jbe  = SELJ(be);
    const float* Jm   = SELJ(m);
    const float* Jv   = SELJ(v);
    float*       Jout = SELJ(out);
    const int    Cin  = SELJ(Cin);
    const int    Och  = SELJ(Ochan);
    const int    relu = SELJ(relu);
#undef SELJ
    const int ob    = by - (in0 ? 0 : (in1 ? n0 : n01));
    const int obase = ob * 32;

    const float* inb = Jin + (size_t)b * Cin * HW;
    const int p0 = blockIdx.x * 256 + tx * 4;

    float acc[8][4];
    #pragma unroll
    for (int j = 0; j < 8; ++j)
        #pragma unroll
        for (int k = 0; k < 4; ++k) acc[j][k] = 0.f;

    const int tid  = ty * 64 + tx;
    const int wrow = tid >> 3;                  // 0..31
    const int wcol = (tid & 7) * 8;             // 0..56
    const float* wbase = Jw + (size_t)(obase + wrow) * Cin + wcol;

    // stage chunk 0 weights into buf 0
    *(float4*)&wlds[0][wrow][wcol]     = *(const float4*)wbase;
    *(float4*)&wlds[0][wrow][wcol + 4] = *(const float4*)(wbase + 4);

    // prefetch first x block (channels 0..3)
    const float* xpf = inb + p0;
    float4 nx0 = *(const float4*)(xpf);
    float4 nx1 = *(const float4*)(xpf + HW);
    float4 nx2 = *(const float4*)(xpf + 2 * HW);
    float4 nx3 = *(const float4*)(xpf + 3 * HW);
    xpf += 4 * HW;

    __syncthreads();

    const int nchunks = Cin >> 6;
    for (int ch = 0; ch < nchunks; ++ch) {
        const int cur = ch & 1;
        if (ch + 1 < nchunks) {                 // stage next chunk (no barrier yet)
            const float* ws2 = wbase + (ch + 1) * 64;
            *(float4*)&wlds[cur ^ 1][wrow][wcol]     = *(const float4*)ws2;
            *(float4*)&wlds[cur ^ 1][wrow][wcol + 4] = *(const float4*)(ws2 + 4);
        }
        #pragma unroll 4
        for (int c4 = 0; c4 < 64; c4 += 4) {
            const float4 x0 = nx0, x1 = nx1, x2 = nx2, x3 = nx3;
            if (ch * 64 + c4 + 4 < Cin) {       // uniform; false only on last step
                nx0 = *(const float4*)(xpf);
                nx1 = *(const float4*)(xpf + HW);
                nx2 = *(const float4*)(xpf + 2 * HW);
                nx3 = *(const float4*)(xpf + 3 * HW);
                xpf += 4 * HW;
            }
            #pragma unroll
            for (int j = 0; j < 8; ++j) {
                const float4 wv = *(const float4*)&wlds[cur][ty * 8 + j][c4];
                acc[j][0] = fmaf(wv.w, x3.x, fmaf(wv.z, x2.x, fmaf(wv.y, x1.x, fmaf(wv.x, x0.x, acc[j][0]))));
                acc[j][1] = fmaf(wv.w, x3.y, fmaf(wv.z, x2.y, fmaf(wv.y, x1.y, fmaf(wv.x, x0.y, acc[j][1]))));
                acc[j][2] = fmaf(wv.w, x3.z, fmaf(wv.z, x2.z, fmaf(wv.y, x1.z, fmaf(wv.x, x0.z, acc[j][2]))));
                acc[j][3] = fmaf(wv.w, x3.w, fmaf(wv.z, x2.w, fmaf(wv.y, x1.w, fmaf(wv.x, x0.w, acc[j][3]))));
            }
        }
        __syncthreads();
    }

    #pragma unroll
    for (int j = 0; j < 8; ++j) {
        const int o = obase + ty * 8 + j;
        float s, off;
        if (Jg != nullptr) {
            s   = Jg[o] * rsqrtf(Jv[o] + EPSBN);
            off = fmaf(Jb[o] - Jm[o], s, Jbe[o]);      // b*s + be - m*s
        } else {
            s   = 1.f;
            off = Jb[o];
        }
        float r0 = fmaf(acc[j][0], s, off);
        float r1 = fmaf(acc[j][1], s, off);
        float r2 = fmaf(acc[j][2], s, off);
        float r3 = fmaf(acc[j][3], s, off);
        if (relu) {
            r0 = fmaxf(r0, 0.f); r1 = fmaxf(r1, 0.f);
            r2 = fmaxf(r2, 0.f); r3 = fmaxf(r3, 0.f);
        }
        *(float4*)(Jout + ((size_t)b * Och + o) * HW + p0) = make_float4(r0, r1, r2, r3);
    }
}

// ---------------------------------------------------------------------------
// Attention, branch-free: clamped indices, arithmetic zeroing of OOB
// neighbors, LDS cross-wave sim reduction. (Round-1 version, measured fast.)
// ---------------------------------------------------------------------------
__global__ __launch_bounds__(256)
void attn_kernel(const float* __restrict__ key, const float* __restrict__ qry,
                 const float* __restrict__ val, float* __restrict__ ctx)
{
    __shared__ float psim[4][NB][64];
    const int tx = threadIdx.x;
    const int ty = threadIdx.y;
    const int b  = blockIdx.y;
    const int p  = blockIdx.x * 64 + tx;
    const int y  = p >> 6;
    const int xc = p & 63;
    const size_t bo = (size_t)b * 256 * HW;
    const float* kb = key + bo;
    const float* qb = qry + bo;
    const float* vb = val + bo;

    int   idx[NB];
    float valf[NB];
    #pragma unroll
    for (int n = 0; n < NB; ++n) {
        const int d  = (n < 9) ? 1 : (n < 18 ? 2 : 4);
        const int i  = (n / 3) % 3 - 1;
        const int j  = n % 3 - 1;
        const int yy = y + i * d, xx = xc + j * d;
        const bool ok = ((unsigned)yy < (unsigned)Hh) && ((unsigned)xx < (unsigned)Ww);
        const int yyc = min(max(yy, 0), Hh - 1);
        const int xxc = min(max(xx, 0), Ww - 1);
        idx[n]  = yyc * Ww + xxc;
        valf[n] = ok ? 1.f : 0.f;
    }

    float sim[NB];
    #pragma unroll
    for (int n = 0; n < NB; ++n) sim[n] = 0.f;

    const int c0 = ty * 64;
    #pragma unroll 2
    for (int c = c0; c < c0 + 64; ++c) {
        const float  qv = qb[(size_t)c * HW + p];
        const float* kc = kb + (size_t)c * HW;
        #pragma unroll
        for (int n = 0; n < NB; ++n)
            sim[n] = fmaf(kc[idx[n]], qv, sim[n]);
    }

    #pragma unroll
    for (int n = 0; n < NB; ++n) psim[ty][n][tx] = sim[n] * valf[n];
    __syncthreads();
    #pragma unroll
    for (int n = 0; n < NB; ++n)
        sim[n] = (psim[0][n][tx] + psim[1][n][tx]) + (psim[2][n][tx] + psim[3][n][tx]);

    float mx = sim[0];
    #pragma unroll
    for (int n = 1; n < NB; ++n) mx = fmaxf(mx, sim[n]);
    float sum = 0.f;
    #pragma unroll
    for (int n = 0; n < NB; ++n) { sim[n] = __expf(sim[n] - mx); sum += sim[n]; }
    const float inv = 1.f / sum;
    #pragma unroll
    for (int n = 0; n < NB; ++n) sim[n] = sim[n] * inv * valf[n];

    #pragma unroll 2
    for (int c = c0; c < c0 + 64; ++c) {
        const float* vc = vb + (size_t)c * HW;
        float a = 0.f;
        #pragma unroll
        for (int n = 0; n < NB; ++n)
            a = fmaf(sim[n], vc[idx[n]], a);
        ctx[bo + (size_t)c * HW + p] = a;
    }
}

extern "C" void kernel_launch(void* const* d_in, const int* in_sizes, int n_in,
                              void* d_out, int out_size, void* d_ws, size_t ws_size,
                              hipStream_t stream)
{
    (void)in_sizes; (void)n_in; (void)out_size; (void)ws_size;
    const float* x     = (const float*)d_in[0];
    const float* k1_w  = (const float*)d_in[1];
    const float* k1_b  = (const float*)d_in[2];
    const float* k1_g  = (const float*)d_in[3];
    const float* k1_be = (const float*)d_in[4];
    const float* k1_m  = (const float*)d_in[5];
    const float* k1_v  = (const float*)d_in[6];
    const float* k2_w  = (const float*)d_in[7];
    const float* k2_b  = (const float*)d_in[8];
    const float* k2_g  = (const float*)d_in[9];
    const float* k2_be = (const float*)d_in[10];
    const float* k2_m  = (const float*)d_in[11];
    const float* k2_v  = (const float*)d_in[12];
    const float* q1_w  = (const float*)d_in[13];
    const float* q1_b  = (const float*)d_in[14];
    const float* q1_g  = (const float*)d_in[15];
    const float* q1_be = (const float*)d_in[16];
    const float* q1_m  = (const float*)d_in[17];
    const float* q1_v  = (const float*)d_in[18];
    const float* q2_w  = (const float*)d_in[19];
    const float* q2_b  = (const float*)d_in[20];
    const float* q2_g  = (const float*)d_in[21];
    const float* q2_be = (const float*)d_in[22];
    const float* q2_m  = (const float*)d_in[23];
    const float* q2_v  = (const float*)d_in[24];
    const float* v_w   = (const float*)d_in[25];
    const float* v_b   = (const float*)d_in[26];
    const float* w_w   = (const float*)d_in[27];
    const float* w_b   = (const float*)d_in[28];

    float* ws = (float*)d_ws;
    const size_t S = (size_t)4 * 256 * HW;
    float* v_buf   = ws;
    float* k1_buf  = ws + S;
    float* q1_buf  = ws + 2 * S;
    float* key_buf = ws + 3 * S;
    float* qry_buf = ws + 4 * S;
    float* ctx_buf = k1_buf;                    // k1 dead after stage 2 -> reuse

    const dim3 blk(64, 4);

    ConvJob jv  = { x,      v_w,  v_b,  nullptr, nullptr, nullptr, nullptr, v_buf,          512, 256, 0 };
    ConvJob jk1 = { x,      k1_w, k1_b, k1_g,    k1_be,   k1_m,    k1_v,    k1_buf,         512, 256, 1 };
    ConvJob jq1 = { x,      q1_w, q1_b, q1_g,    q1_be,   q1_m,    q1_v,    q1_buf,         512, 256, 1 };
    ConvJob jk2 = { k1_buf, k2_w, k2_b, k2_g,    k2_be,   k2_m,    k2_v,    key_buf,        256, 256, 1 };
    ConvJob jq2 = { q1_buf, q2_w, q2_b, q2_g,    q2_be,   q2_m,    q2_v,    qry_buf,        256, 256, 1 };
    ConvJob jw  = { ctx_buf, w_w, w_b,  nullptr, nullptr, nullptr, nullptr, (float*)d_out,  256, 512, 0 };

    // stage 1: v | k1 | q1 fused (each 8 o-blocks) -> 1536 blocks
    conv1x1_fused<<<dim3(16, 24, 4), blk, 0, stream>>>(jv, jk1, jq1, 8, 16);
    // stage 2: k2 | q2 fused -> 1024 blocks
    conv1x1_fused<<<dim3(16, 16, 4), blk, 0, stream>>>(jk2, jq2, jq2, 8, 16);
    // stage 3: attention
    attn_kernel<<<dim3(64, 4), blk, 0, stream>>>(key_buf, qry_buf, v_buf, ctx_buf);
    // stage 4: final conv (256 -> 512), 16 o-blocks -> 1024 blocks
    conv1x1_fused<<<dim3(16, 16, 4), blk, 0, stream>>>(jw, jw, jw, 16, 16);
}

// Round 5
// 249.972 us; speedup vs baseline: 16.0408x; 1.4736x over previous
//
#include <hip/hip_runtime.h>

#define HW   4096
#define Hh   64
#define Ww   64
#define NB   27
#define EPSBN 1e-5f

typedef _Float16 f16x8 __attribute__((ext_vector_type(8)));
typedef _Float16 f16x4 __attribute__((ext_vector_type(4)));
typedef float    f32x4 __attribute__((ext_vector_type(4)));

// ---------------------------------------------------------------------------
// prep: weights f32 -> f16 (same (O,Cin) layout)
// ---------------------------------------------------------------------------
__global__ __launch_bounds__(256)
void cvt_w_kernel(const float* s0, const float* s1, const float* s2,
                  const float* s3, const float* s4, const float* s5,
                  _Float16* d0, _Float16* d1, _Float16* d2,
                  _Float16* d3, _Float16* d4, _Float16* d5)
{
    const int j = blockIdx.y;
    const float* s = j==0?s0: j==1?s1: j==2?s2: j==3?s3: j==4?s4: s5;
    _Float16*  d = j==0?d0: j==1?d1: j==2?d2: j==3?d3: j==4?d4: d5;
    const int  n = (j==3 || j==4) ? 65536 : 131072;
    const int  i = (blockIdx.x * 256 + threadIdx.x) * 8;
    if (i < n) {
        f16x8 h;
        #pragma unroll
        for (int k = 0; k < 8; ++k) h[k] = (_Float16)s[i + k];
        *(f16x8*)(d + i) = h;
    }
}

// ---------------------------------------------------------------------------
// prep: x (b,c,p) f32 -> xT (b,p,c) f16.  Reads coalesced per channel.
// ---------------------------------------------------------------------------
__global__ __launch_bounds__(256)
void cvt_x_kernel(const float* __restrict__ x, _Float16* __restrict__ xT)
{
    const int tx = threadIdx.x;                 // pixel lane
    const int ty = threadIdx.y;                 // channel octet
    const int p  = blockIdx.x * 64 + tx;
    const int c0 = blockIdx.y * 32 + ty * 8;
    const int b  = blockIdx.z;
    const float* xp = x + ((size_t)b * 512 + c0) * HW + p;
    f16x8 h;
    #pragma unroll
    for (int i = 0; i < 8; ++i) h[i] = (_Float16)xp[(size_t)i * HW];
    *(f16x8*)(xT + ((size_t)b * HW + p) * 512 + c0) = h;
}

// ---------------------------------------------------------------------------
// MFMA 1x1-conv (+BN+ReLU when g!=null). f16 inputs, f32 accumulate.
//   in  : (b, p, Cin) f16 (transposed layout) -- B operand, read from GLOBAL
//   w   : (O, Cin) f16                        -- A operand, staged in LDS
//   outh: (b, p, O) f16   and/or  outf: (b, O, p) f32
// Block: 256 thr = 4 waves; tile 64 o x 128 p; wave = 32 o x 64 p
// = 2x4 mfma_f32_16x16x32_f16 tiles, K-loop 32/step, W staged 64c/round.
// Job fields selected with block-uniform ternaries on VALUES (round-3 lesson).
// ---------------------------------------------------------------------------
struct ConvJob {
    const _Float16* in;
    const _Float16* w;
    const float* b; const float* g; const float* be; const float* m; const float* v;
    _Float16* outh;
    float*    outf;
    int Cin; int O;
};

__global__ __launch_bounds__(256)
void conv_mfma(ConvJob J0, ConvJob J1, ConvJob J2, int n0, int n01)
{
    __shared__ _Float16 Wl[64][72];             // 72 = 64 + 8 pad (144B rows, 16B-aligned)
    const int tid = threadIdx.x;
    const int l   = tid & 63;
    const int wv  = tid >> 6;
    const int ow  = wv & 1;                     // o-half of tile
    const int pw  = wv >> 1;                    // p-half of tile
    const int b   = blockIdx.z;

    const int by  = blockIdx.y;
    const bool i0 = by < n0;
    const bool i1 = !i0 && by < n01;
#define SELJ(f) (i0 ? J0.f : (i1 ? J1.f : J2.f))
    const _Float16* Jin  = SELJ(in);
    const _Float16* Jw   = SELJ(w);
    const float* Jb  = SELJ(b);
    const float* Jg  = SELJ(g);
    const float* Jbe = SELJ(be);
    const float* Jm  = SELJ(m);
    const float* Jv  = SELJ(v);
    _Float16* Jouth  = SELJ(outh);
    float*    Joutf  = SELJ(outf);
    const int Cin    = SELJ(Cin);
    const int JO     = SELJ(O);
#undef SELJ
    const int ob    = by - (i0 ? 0 : (i1 ? n0 : n01));
    const int obase = ob * 64;
    const int p0    = blockIdx.x * 128;

    const int lr = l & 15;                      // N/M index within 16x16 tile
    const int lg = l >> 4;                      // k-group (8 contiguous k)

    // per-lane B row pointer (pixel row), k-base lg*8
    const _Float16* bp = Jin + ((size_t)b * HW + p0 + pw * 64 + lr) * (size_t)Cin + lg * 8;

    f32x4 acc[2][4] = {};

    // W staging indices: 512 16B-chunks, thread handles rows wrow & wrow+32
    const int wrow = tid >> 3;                  // 0..31
    const int wcol = (tid & 7) * 8;             // 0..56 (f16)
    const _Float16* wsrc = Jw + (size_t)(obase + wrow) * Cin + wcol;

    // prefetch B for first K-step
    f16x8 bfr[4];
    #pragma unroll
    for (int pt = 0; pt < 4; ++pt)
        bfr[pt] = *(const f16x8*)(bp + (size_t)pt * 16 * Cin);

    const int nr = Cin >> 6;
    for (int rd = 0; rd < nr; ++rd) {
        const _Float16* wsr = wsrc + rd * 64;
        *(f16x8*)&Wl[wrow][wcol]      = *(const f16x8*)(wsr);
        *(f16x8*)&Wl[wrow + 32][wcol] = *(const f16x8*)(wsr + (size_t)32 * Cin);
        __syncthreads();
        #pragma unroll
        for (int ks = 0; ks < 2; ++ks) {
            const int ck = rd * 64 + ks * 32;
            f16x8 bcur[4];
            #pragma unroll
            for (int pt = 0; pt < 4; ++pt) bcur[pt] = bfr[pt];
            if (ck + 32 < Cin) {                // prefetch next K-step (uniform)
                #pragma unroll
                for (int pt = 0; pt < 4; ++pt)
                    bfr[pt] = *(const f16x8*)(bp + (size_t)pt * 16 * Cin + ck + 32);
            }
            f16x8 a0 = *(const f16x8*)&Wl[ow * 32 + lr][ks * 32 + lg * 8];
            f16x8 a1 = *(const f16x8*)&Wl[ow * 32 + 16 + lr][ks * 32 + lg * 8];
            #pragma unroll
            for (int pt = 0; pt < 4; ++pt) {
                acc[0][pt] = __builtin_amdgcn_mfma_f32_16x16x32_f16(a0, bcur[pt], acc[0][pt], 0, 0, 0);
                acc[1][pt] = __builtin_amdgcn_mfma_f32_16x16x32_f16(a1, bcur[pt], acc[1][pt], 0, 0, 0);
            }
        }
        __syncthreads();
    }

    // BN/ReLU coefficients for this lane's 8 output rows
    float sc[2][4], of[2][4];
    const int relu = (Jg != nullptr);
    #pragma unroll
    for (int ot = 0; ot < 2; ++ot)
        #pragma unroll
        for (int r = 0; r < 4; ++r) {
            const int o = obase + ow * 32 + ot * 16 + lg * 4 + r;
            float s, off;
            if (Jg) { s = Jg[o] * rsqrtf(Jv[o] + EPSBN); off = fmaf(Jb[o] - Jm[o], s, Jbe[o]); }
            else    { s = 1.f;                           off = Jb[o]; }
            sc[ot][r] = s; of[ot][r] = off;
        }

    #pragma unroll
    for (int ot = 0; ot < 2; ++ot)
        #pragma unroll
        for (int pt = 0; pt < 4; ++pt) {
            const int p  = p0 + pw * 64 + pt * 16 + lr;
            const int o4 = obase + ow * 32 + ot * 16 + lg * 4;
            float vv[4];
            #pragma unroll
            for (int r = 0; r < 4; ++r) {
                float t = fmaf(acc[ot][pt][r], sc[ot][r], of[ot][r]);
                vv[r] = relu ? fmaxf(t, 0.f) : t;
            }
            if (Jouth) {
                f16x4 h;
                #pragma unroll
                for (int r = 0; r < 4; ++r) h[r] = (_Float16)vv[r];
                *(f16x4*)(Jouth + ((size_t)b * HW + p) * JO + o4) = h;
            }
            if (Joutf) {
                #pragma unroll
                for (int r = 0; r < 4; ++r)
                    Joutf[((size_t)b * JO + o4 + r) * HW + p] = vv[r];
            }
        }
}

// ---------------------------------------------------------------------------
// Attention on transposed f16 buffers (b, p, 256). f32 compute.
// Branch-free clamped indices; OOB zeroed arithmetically; LDS cross-wave
// reduce. Neighbor loads are 16B vectors (channel-contiguous layout).
// ---------------------------------------------------------------------------
__global__ __launch_bounds__(256)
void attn_T(const _Float16* __restrict__ keyT, const _Float16* __restrict__ qryT,
            const _Float16* __restrict__ valT, _Float16* __restrict__ ctxT)
{
    __shared__ float psim[4][NB][64];
    const int tx = threadIdx.x;
    const int ty = threadIdx.y;
    const int b  = blockIdx.y;
    const int p  = blockIdx.x * 64 + tx;
    const int y  = p >> 6;
    const int xc = p & 63;
    const size_t rowb = (size_t)b * HW;

    int   idx[NB];
    float valf[NB];
    #pragma unroll
    for (int n = 0; n < NB; ++n) {
        const int d  = (n < 9) ? 1 : (n < 18 ? 2 : 4);
        const int i  = (n / 3) % 3 - 1;
        const int j  = n % 3 - 1;
        const int yy = y + i * d, xx = xc + j * d;
        const bool ok = ((unsigned)yy < (unsigned)Hh) && ((unsigned)xx < (unsigned)Ww);
        idx[n]  = min(max(yy, 0), Hh - 1) * Ww + min(max(xx, 0), Ww - 1);
        valf[n] = ok ? 1.f : 0.f;
    }

    float sim[NB];
    #pragma unroll
    for (int n = 0; n < NB; ++n) sim[n] = 0.f;

    const int c0 = ty * 64;
    const _Float16* qp = qryT + (rowb + p) * 256 + c0;

    for (int ch = 0; ch < 8; ++ch) {            // 8 chunks of 8 channels
        const f16x8 q8 = *(const f16x8*)(qp + ch * 8);
        float qf[8];
        #pragma unroll
        for (int i = 0; i < 8; ++i) qf[i] = (float)q8[i];
        #pragma unroll
        for (int n = 0; n < NB; ++n) {
            const f16x8 k8 = *(const f16x8*)(keyT + (rowb + idx[n]) * 256 + c0 + ch * 8);
            float s = sim[n];
            #pragma unroll
            for (int i = 0; i < 8; ++i) s = fmaf(qf[i], (float)k8[i], s);
            sim[n] = s;
        }
    }

    #pragma unroll
    for (int n = 0; n < NB; ++n) psim[ty][n][tx] = sim[n] * valf[n];
    __syncthreads();
    #pragma unroll
    for (int n = 0; n < NB; ++n)
        sim[n] = (psim[0][n][tx] + psim[1][n][tx]) + (psim[2][n][tx] + psim[3][n][tx]);

    float mx = sim[0];
    #pragma unroll
    for (int n = 1; n < NB; ++n) mx = fmaxf(mx, sim[n]);
    float sum = 0.f;
    #pragma unroll
    for (int n = 0; n < NB; ++n) { sim[n] = __expf(sim[n] - mx); sum += sim[n]; }
    const float inv = 1.f / sum;
    #pragma unroll
    for (int n = 0; n < NB; ++n) sim[n] = sim[n] * inv * valf[n];

    for (int ch = 0; ch < 8; ++ch) {
        float a8[8];
        #pragma unroll
        for (int i = 0; i < 8; ++i) a8[i] = 0.f;
        #pragma unroll
        for (int n = 0; n < NB; ++n) {
            const f16x8 v8 = *(const f16x8*)(valT + (rowb + idx[n]) * 256 + c0 + ch * 8);
            #pragma unroll
            for (int i = 0; i < 8; ++i) a8[i] = fmaf(sim[n], (float)v8[i], a8[i]);
        }
        f16x8 h;
        #pragma unroll
        for (int i = 0; i < 8; ++i) h[i] = (_Float16)a8[i];
        *(f16x8*)(ctxT + (rowb + p) * 256 + c0 + ch * 8) = h;
    }
}

extern "C" void kernel_launch(void* const* d_in, const int* in_sizes, int n_in,
                              void* d_out, int out_size, void* d_ws, size_t ws_size,
                              hipStream_t stream)
{
    (void)in_sizes; (void)n_in; (void)out_size; (void)ws_size;
    const float* x     = (const float*)d_in[0];
    const float* k1_w  = (const float*)d_in[1];
    const float* k1_b  = (const float*)d_in[2];
    const float* k1_g  = (const float*)d_in[3];
    const float* k1_be = (const float*)d_in[4];
    const float* k1_m  = (const float*)d_in[5];
    const float* k1_v  = (const float*)d_in[6];
    const float* k2_w  = (const float*)d_in[7];
    const float* k2_b  = (const float*)d_in[8];
    const float* k2_g  = (const float*)d_in[9];
    const float* k2_be = (const float*)d_in[10];
    const float* k2_m  = (const float*)d_in[11];
    const float* k2_v  = (const float*)d_in[12];
    const float* q1_w  = (const float*)d_in[13];
    const float* q1_b  = (const float*)d_in[14];
    const float* q1_g  = (const float*)d_in[15];
    const float* q1_be = (const float*)d_in[16];
    const float* q1_m  = (const float*)d_in[17];
    const float* q1_v  = (const float*)d_in[18];
    const float* q2_w  = (const float*)d_in[19];
    const float* q2_b  = (const float*)d_in[20];
    const float* q2_g  = (const float*)d_in[21];
    const float* q2_be = (const float*)d_in[22];
    const float* q2_m  = (const float*)d_in[23];
    const float* q2_v  = (const float*)d_in[24];
    const float* v_w   = (const float*)d_in[25];
    const float* v_b   = (const float*)d_in[26];
    const float* w_w   = (const float*)d_in[27];
    const float* w_b   = (const float*)d_in[28];

    _Float16* hw = (_Float16*)d_ws;
    const size_t SX = (size_t)4 * HW * 512;     // 8,388,608 f16
    const size_t SH = (size_t)4 * HW * 256;     // 4,194,304 f16
    _Float16* xT    = hw;
    _Float16* wv_h  = xT + SX;
    _Float16* wk1_h = wv_h  + 131072;
    _Float16* wq1_h = wk1_h + 131072;
    _Float16* wk2_h = wq1_h + 131072;
    _Float16* wq2_h = wk2_h + 65536;
    _Float16* ww_h  = wq2_h + 65536;
    _Float16* k1T   = ww_h  + 131072;
    _Float16* q1T   = k1T + SH;
    _Float16* valT  = q1T + SH;
    _Float16* keyT  = valT + SH;
    _Float16* qryT  = keyT + SH;
    _Float16* ctxT  = qryT + SH;

    // prep: weights + x to f16 (x also transposed to (b,p,c))
    cvt_w_kernel<<<dim3(64, 6), 256, 0, stream>>>(v_w, k1_w, q1_w, k2_w, q2_w, w_w,
                                                  wv_h, wk1_h, wq1_h, wk2_h, wq2_h, ww_h);
    cvt_x_kernel<<<dim3(64, 16, 4), dim3(64, 4), 0, stream>>>(x, xT);

    ConvJob jv  = { xT,   wv_h,  v_b,  nullptr, nullptr, nullptr, nullptr, valT, nullptr, 512, 256 };
    ConvJob jk1 = { xT,   wk1_h, k1_b, k1_g, k1_be, k1_m, k1_v,            k1T,  nullptr, 512, 256 };
    ConvJob jq1 = { xT,   wq1_h, q1_b, q1_g, q1_be, q1_m, q1_v,            q1T,  nullptr, 512, 256 };
    ConvJob jk2 = { k1T,  wk2_h, k2_b, k2_g, k2_be, k2_m, k2_v,            keyT, nullptr, 256, 256 };
    ConvJob jq2 = { q1T,  wq2_h, q2_b, q2_g, q2_be, q2_m, q2_v,            qryT, nullptr, 256, 256 };
    ConvJob jw  = { ctxT, ww_h,  w_b,  nullptr, nullptr, nullptr, nullptr, nullptr, (float*)d_out, 256, 512 };

    // stage 1: v | k1 | q1  (4 o-blocks each)
    conv_mfma<<<dim3(32, 12, 4), 256, 0, stream>>>(jv, jk1, jq1, 4, 8);
    // stage 2: k2 | q2
    conv_mfma<<<dim3(32, 8, 4), 256, 0, stream>>>(jk2, jq2, jq2, 4, 8);
    // stage 3: attention
    attn_T<<<dim3(64, 4), dim3(64, 4), 0, stream>>>(keyT, qryT, valT, ctxT);
    // stage 4: final conv -> f32 d_out
    conv_mfma<<<dim3(32, 8, 4), 256, 0, stream>>>(jw, jw, jw, 8, 8);
}

// Round 6
// 153.868 us; speedup vs baseline: 26.0597x; 1.6246x over previous
//
#include <hip/hip_runtime.h>

#define HW   4096
#define Hh   64
#define Ww   64
#define NB   27
#define EPSBN 1e-5f

typedef _Float16 f16x8 __attribute__((ext_vector_type(8)));
typedef _Float16 f16x4 __attribute__((ext_vector_type(4)));
typedef float    f32x4 __attribute__((ext_vector_type(4)));

// ---------------------------------------------------------------------------
// prep: weights f32 -> f16 (same (O,Cin) layout)
// ---------------------------------------------------------------------------
__global__ __launch_bounds__(256)
void cvt_w_kernel(const float* s0, const float* s1, const float* s2,
                  const float* s3, const float* s4, const float* s5,
                  _Float16* d0, _Float16* d1, _Float16* d2,
                  _Float16* d3, _Float16* d4, _Float16* d5)
{
    const int j = blockIdx.y;
    const float* s = j==0?s0: j==1?s1: j==2?s2: j==3?s3: j==4?s4: s5;
    _Float16*  d = j==0?d0: j==1?d1: j==2?d2: j==3?d3: j==4?d4: d5;
    const int  n = (j==3 || j==4) ? 65536 : 131072;
    const int  i = (blockIdx.x * 256 + threadIdx.x) * 8;
    if (i < n) {
        f16x8 h;
        #pragma unroll
        for (int k = 0; k < 8; ++k) h[k] = (_Float16)s[i + k];
        *(f16x8*)(d + i) = h;
    }
}

// ---------------------------------------------------------------------------
// prep: x (b,c,p) f32 -> xT (b,p,c) f16.  Reads coalesced per channel.
// ---------------------------------------------------------------------------
__global__ __launch_bounds__(256)
void cvt_x_kernel(const float* __restrict__ x, _Float16* __restrict__ xT)
{
    const int tx = threadIdx.x;
    const int ty = threadIdx.y;
    const int p  = blockIdx.x * 64 + tx;
    const int c0 = blockIdx.y * 32 + ty * 8;
    const int b  = blockIdx.z;
    const float* xp = x + ((size_t)b * 512 + c0) * HW + p;
    f16x8 h;
    #pragma unroll
    for (int i = 0; i < 8; ++i) h[i] = (_Float16)xp[(size_t)i * HW];
    *(f16x8*)(xT + ((size_t)b * HW + p) * 512 + c0) = h;
}

// ---------------------------------------------------------------------------
// MFMA 1x1-conv (+BN+ReLU when g!=null). f16 inputs, f32 accumulate.
//   in   : (b, p, Cin) f16 -- B operand, read from GLOBAL per-lane
//   w    : (O, Cin) f16    -- A operand, staged in LDS
//   outh : (b, p, O) f16 | outt : (b, O, p) f16 | outf : (b, O, p) f32
// Block: 4 waves; tile 64 o x 128 p; wave = 32 o x 64 p (2x4 16x16x32 tiles).
// Job fields selected with block-uniform ternaries on VALUES (round-3 lesson).
// ---------------------------------------------------------------------------
struct ConvJob {
    const _Float16* in;
    const _Float16* w;
    const float* b; const float* g; const float* be; const float* m; const float* v;
    _Float16* outh;
    _Float16* outt;
    float*    outf;
    int Cin; int O;
};

__global__ __launch_bounds__(256)
void conv_mfma(ConvJob J0, ConvJob J1, ConvJob J2, int n0, int n01)
{
    __shared__ _Float16 Wl[64][72];
    const int tid = threadIdx.x;
    const int l   = tid & 63;
    const int wv  = tid >> 6;
    const int ow  = wv & 1;
    const int pw  = wv >> 1;
    const int b   = blockIdx.z;

    const int by  = blockIdx.y;
    const bool i0 = by < n0;
    const bool i1 = !i0 && by < n01;
#define SELJ(f) (i0 ? J0.f : (i1 ? J1.f : J2.f))
    const _Float16* Jin  = SELJ(in);
    const _Float16* Jw   = SELJ(w);
    const float* Jb  = SELJ(b);
    const float* Jg  = SELJ(g);
    const float* Jbe = SELJ(be);
    const float* Jm  = SELJ(m);
    const float* Jv  = SELJ(v);
    _Float16* Jouth  = SELJ(outh);
    _Float16* Joutt  = SELJ(outt);
    float*    Joutf  = SELJ(outf);
    const int Cin    = SELJ(Cin);
    const int JO     = SELJ(O);
#undef SELJ
    const int ob    = by - (i0 ? 0 : (i1 ? n0 : n01));
    const int obase = ob * 64;
    const int p0    = blockIdx.x * 128;

    const int lr = l & 15;
    const int lg = l >> 4;

    const _Float16* bp = Jin + ((size_t)b * HW + p0 + pw * 64 + lr) * (size_t)Cin + lg * 8;

    f32x4 acc[2][4] = {};

    const int wrow = tid >> 3;
    const int wcol = (tid & 7) * 8;
    const _Float16* wsrc = Jw + (size_t)(obase + wrow) * Cin + wcol;

    f16x8 bfr[4];
    #pragma unroll
    for (int pt = 0; pt < 4; ++pt)
        bfr[pt] = *(const f16x8*)(bp + (size_t)pt * 16 * Cin);

    const int nr = Cin >> 6;
    for (int rd = 0; rd < nr; ++rd) {
        const _Float16* wsr = wsrc + rd * 64;
        *(f16x8*)&Wl[wrow][wcol]      = *(const f16x8*)(wsr);
        *(f16x8*)&Wl[wrow + 32][wcol] = *(const f16x8*)(wsr + (size_t)32 * Cin);
        __syncthreads();
        #pragma unroll
        for (int ks = 0; ks < 2; ++ks) {
            const int ck = rd * 64 + ks * 32;
            f16x8 bcur[4];
            #pragma unroll
            for (int pt = 0; pt < 4; ++pt) bcur[pt] = bfr[pt];
            if (ck + 32 < Cin) {
                #pragma unroll
                for (int pt = 0; pt < 4; ++pt)
                    bfr[pt] = *(const f16x8*)(bp + (size_t)pt * 16 * Cin + ck + 32);
            }
            f16x8 a0 = *(const f16x8*)&Wl[ow * 32 + lr][ks * 32 + lg * 8];
            f16x8 a1 = *(const f16x8*)&Wl[ow * 32 + 16 + lr][ks * 32 + lg * 8];
            #pragma unroll
            for (int pt = 0; pt < 4; ++pt) {
                acc[0][pt] = __builtin_amdgcn_mfma_f32_16x16x32_f16(a0, bcur[pt], acc[0][pt], 0, 0, 0);
                acc[1][pt] = __builtin_amdgcn_mfma_f32_16x16x32_f16(a1, bcur[pt], acc[1][pt], 0, 0, 0);
            }
        }
        __syncthreads();
    }

    float sc[2][4], of[2][4];
    const int relu = (Jg != nullptr);
    #pragma unroll
    for (int ot = 0; ot < 2; ++ot)
        #pragma unroll
        for (int r = 0; r < 4; ++r) {
            const int o = obase + ow * 32 + ot * 16 + lg * 4 + r;
            float s, off;
            if (Jg) { s = Jg[o] * rsqrtf(Jv[o] + EPSBN); off = fmaf(Jb[o] - Jm[o], s, Jbe[o]); }
            else    { s = 1.f;                           off = Jb[o]; }
            sc[ot][r] = s; of[ot][r] = off;
        }

    #pragma unroll
    for (int ot = 0; ot < 2; ++ot)
        #pragma unroll
        for (int pt = 0; pt < 4; ++pt) {
            const int p  = p0 + pw * 64 + pt * 16 + lr;
            const int o4 = obase + ow * 32 + ot * 16 + lg * 4;
            float vv[4];
            #pragma unroll
            for (int r = 0; r < 4; ++r) {
                float t = fmaf(acc[ot][pt][r], sc[ot][r], of[ot][r]);
                vv[r] = relu ? fmaxf(t, 0.f) : t;
            }
            if (Jouth) {
                f16x4 h;
                #pragma unroll
                for (int r = 0; r < 4; ++r) h[r] = (_Float16)vv[r];
                *(f16x4*)(Jouth + ((size_t)b * HW + p) * JO + o4) = h;
            }
            if (Joutt) {
                #pragma unroll
                for (int r = 0; r < 4; ++r)
                    Joutt[((size_t)b * JO + o4 + r) * HW + p] = (_Float16)vv[r];
            }
            if (Joutf) {
                #pragma unroll
                for (int r = 0; r < 4; ++r)
                    Joutf[((size_t)b * JO + o4 + r) * HW + p] = vv[r];
            }
        }
}

// ---------------------------------------------------------------------------
// sim + softmax: K,Q in (b,c,p) f16 (channel-major => lane-contiguous pixel
// reads). Block = 512 thr = 8 waves; wave ty owns 32 channels; LDS reduce.
// Writes prob (b, 27, p) f32 with OOB neighbors zeroed.
// ---------------------------------------------------------------------------
__global__ __launch_bounds__(512)
void sim_softmax(const _Float16* __restrict__ key, const _Float16* __restrict__ qry,
                 float* __restrict__ prob)
{
    __shared__ float psim[8][NB][64];
    const int tid = threadIdx.x;
    const int tx  = tid & 63;
    const int ty  = tid >> 6;                   // 0..7
    const int b   = blockIdx.y;
    const int p   = blockIdx.x * 64 + tx;
    const int y   = p >> 6;
    const int xc  = p & 63;

    int   idx[NB];
    float valf[NB];
    #pragma unroll
    for (int n = 0; n < NB; ++n) {
        const int d  = (n < 9) ? 1 : (n < 18 ? 2 : 4);
        const int i  = (n / 3) % 3 - 1;
        const int j  = n % 3 - 1;
        const int yy = y + i * d, xx = xc + j * d;
        const bool ok = ((unsigned)yy < (unsigned)Hh) && ((unsigned)xx < (unsigned)Ww);
        idx[n]  = min(max(yy, 0), Hh - 1) * Ww + min(max(xx, 0), Ww - 1);
        valf[n] = ok ? 1.f : 0.f;
    }

    float sim[NB];
    #pragma unroll
    for (int n = 0; n < NB; ++n) sim[n] = 0.f;

    const int c0 = ty * 32;
    #pragma unroll 2
    for (int c = c0; c < c0 + 32; ++c) {
        const _Float16* kc = key + ((size_t)b * 256 + c) * HW;
        const float qv = (float)qry[((size_t)b * 256 + c) * HW + p];
        #pragma unroll
        for (int n = 0; n < NB; ++n)
            sim[n] = fmaf((float)kc[idx[n]], qv, sim[n]);
    }

    #pragma unroll
    for (int n = 0; n < NB; ++n) psim[ty][n][tx] = sim[n] * valf[n];
    __syncthreads();
    #pragma unroll
    for (int n = 0; n < NB; ++n) {
        float s = 0.f;
        #pragma unroll
        for (int g = 0; g < 8; ++g) s += psim[g][n][tx];
        sim[n] = s;
    }

    float mx = sim[0];
    #pragma unroll
    for (int n = 1; n < NB; ++n) mx = fmaxf(mx, sim[n]);
    float sum = 0.f;
    #pragma unroll
    for (int n = 0; n < NB; ++n) { sim[n] = __expf(sim[n] - mx); sum += sim[n]; }
    const float inv = 1.f / sum;

    if (ty == 0) {
        #pragma unroll
        for (int n = 0; n < NB; ++n)
            prob[((size_t)b * NB + n) * HW + p] = sim[n] * inv * valf[n];
    }
}

// ---------------------------------------------------------------------------
// PV: ctx(p,c) = sum_n prob[n][p] * V[idx(n,p)][c].  V/ctx in (b,p,256) f16.
// Thread = (pixel, 8-ch slot); 32 consecutive threads read one full 512B
// neighbor row coalesced; prob loads broadcast across the 32.
// ---------------------------------------------------------------------------
__global__ __launch_bounds__(256)
void pv_kernel(const float* __restrict__ prob, const _Float16* __restrict__ valT,
               _Float16* __restrict__ ctxT)
{
    const int tid  = threadIdx.x;
    const int slot = tid & 31;                  // 8-channel slot
    const int b    = blockIdx.y;
    const int p    = blockIdx.x * 8 + (tid >> 5);
    const int y    = p >> 6;
    const int xc   = p & 63;

    int idx[NB];
    #pragma unroll
    for (int n = 0; n < NB; ++n) {
        const int d  = (n < 9) ? 1 : (n < 18 ? 2 : 4);
        const int i  = (n / 3) % 3 - 1;
        const int j  = n % 3 - 1;
        idx[n] = min(max(y + i * d, 0), Hh - 1) * Ww + min(max(xc + j * d, 0), Ww - 1);
    }

    const float* pr = prob + (size_t)b * NB * HW + p;
    const _Float16* vb = valT + (size_t)b * HW * 256 + slot * 8;

    float acc[8];
    #pragma unroll
    for (int i = 0; i < 8; ++i) acc[i] = 0.f;

    #pragma unroll
    for (int n = 0; n < NB; ++n) {
        const float w = pr[(size_t)n * HW];
        const f16x8 v8 = *(const f16x8*)(vb + (size_t)idx[n] * 256);
        #pragma unroll
        for (int i = 0; i < 8; ++i) acc[i] = fmaf(w, (float)v8[i], acc[i]);
    }

    f16x8 h;
    #pragma unroll
    for (int i = 0; i < 8; ++i) h[i] = (_Float16)acc[i];
    *(f16x8*)(ctxT + ((size_t)b * HW + p) * 256 + slot * 8) = h;
}

extern "C" void kernel_launch(void* const* d_in, const int* in_sizes, int n_in,
                              void* d_out, int out_size, void* d_ws, size_t ws_size,
                              hipStream_t stream)
{
    (void)in_sizes; (void)n_in; (void)out_size; (void)ws_size;
    const float* x     = (const float*)d_in[0];
    const float* k1_w  = (const float*)d_in[1];
    const float* k1_b  = (const float*)d_in[2];
    const float* k1_g  = (const float*)d_in[3];
    const float* k1_be = (const float*)d_in[4];
    const float* k1_m  = (const float*)d_in[5];
    const float* k1_v  = (const float*)d_in[6];
    const float* k2_w  = (const float*)d_in[7];
    const float* k2_b  = (const float*)d_in[8];
    const float* k2_g  = (const float*)d_in[9];
    const float* k2_be = (const float*)d_in[10];
    const float* k2_m  = (const float*)d_in[11];
    const float* k2_v  = (const float*)d_in[12];
    const float* q1_w  = (const float*)d_in[13];
    const float* q1_b  = (const float*)d_in[14];
    const float* q1_g  = (const float*)d_in[15];
    const float* q1_be = (const float*)d_in[16];
    const float* q1_m  = (const float*)d_in[17];
    const float* q1_v  = (const float*)d_in[18];
    const float* q2_w  = (const float*)d_in[19];
    const float* q2_b  = (const float*)d_in[20];
    const float* q2_g  = (const float*)d_in[21];
    const float* q2_be = (const float*)d_in[22];
    const float* q2_m  = (const float*)d_in[23];
    const float* q2_v  = (const float*)d_in[24];
    const float* v_w   = (const float*)d_in[25];
    const float* v_b   = (const float*)d_in[26];
    const float* w_w   = (const float*)d_in[27];
    const float* w_b   = (const float*)d_in[28];

    _Float16* hw = (_Float16*)d_ws;
    const size_t SX = (size_t)4 * HW * 512;
    const size_t SH = (size_t)4 * HW * 256;
    _Float16* xT    = hw;
    _Float16* wv_h  = xT + SX;
    _Float16* wk1_h = wv_h  + 131072;
    _Float16* wq1_h = wk1_h + 131072;
    _Float16* wq1b  = wq1_h + 131072;   // k2
    _Float16* wq2_h = wq1b  + 65536;
    _Float16* ww_h  = wq2_h + 65536;
    _Float16* k1T   = ww_h  + 131072;
    _Float16* q1T   = k1T + SH;
    _Float16* valT  = q1T + SH;
    _Float16* ctxT  = valT + SH;
    _Float16* keyCP = ctxT + SH;        // (b,c,p) f16
    _Float16* qryCP = keyCP + SH;
    float*    prob  = (float*)(qryCP + SH);   // (b,27,p) f32

    cvt_w_kernel<<<dim3(64, 6), 256, 0, stream>>>(v_w, k1_w, q1_w, k2_w, q2_w, w_w,
                                                  wv_h, wk1_h, wq1_h, wq1b, wq2_h, ww_h);
    cvt_x_kernel<<<dim3(64, 16, 4), dim3(64, 4), 0, stream>>>(x, xT);

    ConvJob jv  = { xT,   wv_h,  v_b,  nullptr, nullptr, nullptr, nullptr, valT,    nullptr, nullptr, 512, 256 };
    ConvJob jk1 = { xT,   wk1_h, k1_b, k1_g, k1_be, k1_m, k1_v,            k1T,     nullptr, nullptr, 512, 256 };
    ConvJob jq1 = { xT,   wq1_h, q1_b, q1_g, q1_be, q1_m, q1_v,            q1T,     nullptr, nullptr, 512, 256 };
    ConvJob jk2 = { k1T,  wq1b,  k2_b, k2_g, k2_be, k2_m, k2_v,            nullptr, keyCP,   nullptr, 256, 256 };
    ConvJob jq2 = { q1T,  wq2_h, q2_b, q2_g, q2_be, q2_m, q2_v,            nullptr, qryCP,   nullptr, 256, 256 };
    ConvJob jw  = { ctxT, ww_h,  w_b,  nullptr, nullptr, nullptr, nullptr, nullptr, nullptr, (float*)d_out, 256, 512 };

    // stage 1: v | k1 | q1
    conv_mfma<<<dim3(32, 12, 4), 256, 0, stream>>>(jv, jk1, jq1, 4, 8);
    // stage 2: k2 | q2 -> (c,p) f16 key/qry
    conv_mfma<<<dim3(32, 8, 4), 256, 0, stream>>>(jk2, jq2, jq2, 4, 8);
    // stage 3a: sim + softmax -> prob
    sim_softmax<<<dim3(64, 4), 512, 0, stream>>>(keyCP, qryCP, prob);
    // stage 3b: PV -> ctxT (p,c) f16
    pv_kernel<<<dim3(512, 4), 256, 0, stream>>>(prob, valT, ctxT);
    // stage 4: final conv -> f32 d_out
    conv_mfma<<<dim3(32, 8, 4), 256, 0, stream>>>(jw, jw, jw, 8, 8);
}

// Round 7
// 106.753 us; speedup vs baseline: 37.5610x; 1.4413x over previous
//
#include <hip/hip_runtime.h>

#define HW   4096
#define Hh   64
#define Ww   64
#define NB   27
#define EPSBN 1e-5f

typedef _Float16 f16x8 __attribute__((ext_vector_type(8)));
typedef _Float16 f16x4 __attribute__((ext_vector_type(4)));
typedef float    f32x4 __attribute__((ext_vector_type(4)));

// async global->LDS, 16B per lane; LDS dest = wave-uniform base + lane*16
__device__ __forceinline__ void gld_lds16(const void* g, void* l) {
    __builtin_amdgcn_global_load_lds(
        (const __attribute__((address_space(1))) unsigned int*)g,
        (__attribute__((address_space(3))) unsigned int*)l, 16, 0, 0);
}

// ---------------------------------------------------------------------------
// prep: weights f32 -> f16 (same (O,Cin) layout)
// ---------------------------------------------------------------------------
__global__ __launch_bounds__(256)
void cvt_w_kernel(const float* s0, const float* s1, const float* s2,
                  const float* s3, const float* s4, const float* s5,
                  _Float16* d0, _Float16* d1, _Float16* d2,
                  _Float16* d3, _Float16* d4, _Float16* d5)
{
    const int j = blockIdx.y;
    const float* s = j==0?s0: j==1?s1: j==2?s2: j==3?s3: j==4?s4: s5;
    _Float16*  d = j==0?d0: j==1?d1: j==2?d2: j==3?d3: j==4?d4: d5;
    const int  n = (j==3 || j==4) ? 65536 : 131072;
    const int  i = (blockIdx.x * 256 + threadIdx.x) * 8;
    if (i < n) {
        f16x8 h;
        #pragma unroll
        for (int k = 0; k < 8; ++k) h[k] = (_Float16)s[i + k];
        *(f16x8*)(d + i) = h;
    }
}

// ---------------------------------------------------------------------------
// prep: x (b,c,p) f32 -> xT (b,p,c) f16.
// ---------------------------------------------------------------------------
__global__ __launch_bounds__(256)
void cvt_x_kernel(const float* __restrict__ x, _Float16* __restrict__ xT)
{
    const int tx = threadIdx.x;
    const int ty = threadIdx.y;
    const int p  = blockIdx.x * 64 + tx;
    const int c0 = blockIdx.y * 32 + ty * 8;
    const int b  = blockIdx.z;
    const float* xp = x + ((size_t)b * 512 + c0) * HW + p;
    f16x8 h;
    #pragma unroll
    for (int i = 0; i < 8; ++i) h[i] = (_Float16)xp[(size_t)i * HW];
    *(f16x8*)(xT + ((size_t)b * HW + p) * 512 + c0) = h;
}

// ---------------------------------------------------------------------------
// m97-style GEMM: C[M, 16384] = W[M,K] x inT[16384,K]^T   (both K-contig)
// 128x128 tile, BK=64. 4 waves, each 64x64 (4x4 16x16x32 f16 MFMA frags).
// A+B tiles staged via global_load_lds w=16 (coalesced); LDS rows XOR-swizzled
// (col_byte ^= (row&7)<<4) by PRE-SWIZZLING the per-lane global source (the
// LDS dest of global_load_lds must stay linear) and applying the same XOR on
// the ds_read side -> conflict-free stride-128B fragment reads.
// Jobs (different weights/outputs, same shape) selected per m-block with
// block-uniform VALUE ternaries (round-3 scratch-spill lesson).
// mode: 0 = f16 out (p,c);  1 = f16 out (b,c,p);  2 = f32 out (b,c,p)
// ---------------------------------------------------------------------------
struct GJob {
    const _Float16* in;   // (16384, K) f16
    const _Float16* w;    // (O, K) f16
    const float* b; const float* g; const float* be; const float* m; const float* v;
    _Float16* oh;
    float*    of;
};

__global__ __launch_bounds__(256)
void gemm128(GJob J0, GJob J1, GJob J2, int nmb0, int nmb01,
             int K, int JO, int mode)
{
    __shared__ _Float16 As[128 * 64];
    __shared__ _Float16 Bs[128 * 64];

    const int tid  = threadIdx.x;
    const int lane = tid & 63;
    const int w    = tid >> 6;                  // wave 0..3
    const int lr   = lane & 15;
    const int lg   = lane >> 4;
    const int wm   = w & 1;                     // M half of tile
    const int wn   = w >> 1;                    // N half of tile

    // XCD-aware swizzle of the n-block (128 % 8 == 0 -> bijective)
    const int bx = blockIdx.x;
    const int nb = (bx & 7) * 16 + (bx >> 3);
    const int mb = blockIdx.y;

    const bool i0 = mb < nmb0;
    const bool i1 = !i0 && mb < nmb01;
#define SELJ(f) (i0 ? J0.f : (i1 ? J1.f : J2.f))
    const _Float16* Jin = SELJ(in);
    const _Float16* Jw  = SELJ(w);
    const float* Jb  = SELJ(b);
    const float* Jg  = SELJ(g);
    const float* Jbe = SELJ(be);
    const float* Jm  = SELJ(m);
    const float* Jv  = SELJ(v);
    _Float16* Joh = SELJ(oh);
    float*    Jof = SELJ(of);
#undef SELJ
    const int obase = (mb - (i0 ? 0 : (i1 ? nmb0 : nmb01))) * 128;

    // staging source: lane covers (row = w*32 + j*8 + lane/8, 16B of cols),
    // source col pre-swizzled so linear LDS ends up XOR-swizzled
    const int rowS = w * 32 + (lane >> 3);          // + j*8
    const int scol = (((lane & 7) ^ (lane >> 3)) << 3);   // f16 units
    const _Float16* aSrc = Jw  + (size_t)(obase + rowS) * K + scol;
    const _Float16* bSrc = Jin + (size_t)(nb * 128 + rowS) * K + scol;
    char* aDst = (char*)As + w * 4096;              // + j*1024 (+ lane*16 by HW)
    char* bDst = (char*)Bs + w * 4096;

    f32x4 acc[4][4] = {};

    const int nr = K >> 6;
    for (int rd = 0; rd < nr; ++rd) {
        __syncthreads();                            // prev compute done
        const int kb = rd * 64;
        #pragma unroll
        for (int j = 0; j < 4; ++j)
            gld_lds16(aSrc + (size_t)j * 8 * K + kb, aDst + j * 1024);
        #pragma unroll
        for (int j = 0; j < 4; ++j)
            gld_lds16(bSrc + (size_t)j * 8 * K + kb, bDst + j * 1024);
        __syncthreads();                            // vmcnt drained here

        #pragma unroll
        for (int ks = 0; ks < 2; ++ks) {
            const int colx = (ks * 64 + lg * 16) ^ ((lr & 7) << 4);
            f16x8 afr[4], bfr[4];
            #pragma unroll
            for (int t = 0; t < 4; ++t) {
                afr[t] = *(const f16x8*)((const char*)As + (wm * 64 + t * 16 + lr) * 128 + colx);
                bfr[t] = *(const f16x8*)((const char*)Bs + (wn * 64 + t * 16 + lr) * 128 + colx);
            }
            #pragma unroll
            for (int ai = 0; ai < 4; ++ai)
                #pragma unroll
                for (int bj = 0; bj < 4; ++bj)
                    acc[ai][bj] = __builtin_amdgcn_mfma_f32_16x16x32_f16(
                        afr[ai], bfr[bj], acc[ai][bj], 0, 0, 0);
        }
    }

    const int relu = (Jg != nullptr);
    #pragma unroll
    for (int ai = 0; ai < 4; ++ai) {
        const int o4 = obase + wm * 64 + ai * 16 + lg * 4;
        float sc[4], of_[4];
        #pragma unroll
        for (int r = 0; r < 4; ++r) {
            const int o = o4 + r;
            if (Jg) { float s = Jg[o] * rsqrtf(Jv[o] + EPSBN); sc[r] = s; of_[r] = fmaf(Jb[o] - Jm[o], s, Jbe[o]); }
            else    { sc[r] = 1.f; of_[r] = Jb[o]; }
        }
        #pragma unroll
        for (int bj = 0; bj < 4; ++bj) {
            const int pg = nb * 128 + wn * 64 + bj * 16 + lr;   // global pixel row
            float vv[4];
            #pragma unroll
            for (int r = 0; r < 4; ++r) {
                float t = fmaf(acc[ai][bj][r], sc[r], of_[r]);
                vv[r] = relu ? fmaxf(t, 0.f) : t;
            }
            if (mode == 0) {
                f16x4 h;
                #pragma unroll
                for (int r = 0; r < 4; ++r) h[r] = (_Float16)vv[r];
                *(f16x4*)(Joh + (size_t)pg * JO + o4) = h;
            } else if (mode == 1) {
                #pragma unroll
                for (int r = 0; r < 4; ++r)
                    Joh[((size_t)(pg >> 12) * JO + o4 + r) * HW + (pg & 4095)] = (_Float16)vv[r];
            } else {
                #pragma unroll
                for (int r = 0; r < 4; ++r)
                    Jof[((size_t)(pg >> 12) * JO + o4 + r) * HW + (pg & 4095)] = vv[r];
            }
        }
    }
}

// ---------------------------------------------------------------------------
// sim + softmax: K,Q in (b,c,p) f16. 512 thr = 8 waves x 32 ch; LDS reduce.
// Writes prob (b,27,p) f32 with OOB neighbors zeroed.
// ---------------------------------------------------------------------------
__global__ __launch_bounds__(512)
void sim_softmax(const _Float16* __restrict__ key, const _Float16* __restrict__ qry,
                 float* __restrict__ prob)
{
    __shared__ float psim[8][NB][64];
    const int tid = threadIdx.x;
    const int tx  = tid & 63;
    const int ty  = tid >> 6;
    const int b   = blockIdx.y;
    const int p   = blockIdx.x * 64 + tx;
    const int y   = p >> 6;
    const int xc  = p & 63;

    int   idx[NB];
    float valf[NB];
    #pragma unroll
    for (int n = 0; n < NB; ++n) {
        const int d  = (n < 9) ? 1 : (n < 18 ? 2 : 4);
        const int i  = (n / 3) % 3 - 1;
        const int j  = n % 3 - 1;
        const int yy = y + i * d, xx = xc + j * d;
        const bool ok = ((unsigned)yy < (unsigned)Hh) && ((unsigned)xx < (unsigned)Ww);
        idx[n]  = min(max(yy, 0), Hh - 1) * Ww + min(max(xx, 0), Ww - 1);
        valf[n] = ok ? 1.f : 0.f;
    }

    float sim[NB];
    #pragma unroll
    for (int n = 0; n < NB; ++n) sim[n] = 0.f;

    const int c0 = ty * 32;
    #pragma unroll 2
    for (int c = c0; c < c0 + 32; ++c) {
        const _Float16* kc = key + ((size_t)b * 256 + c) * HW;
        const float qv = (float)qry[((size_t)b * 256 + c) * HW + p];
        #pragma unroll
        for (int n = 0; n < NB; ++n)
            sim[n] = fmaf((float)kc[idx[n]], qv, sim[n]);
    }

    #pragma unroll
    for (int n = 0; n < NB; ++n) psim[ty][n][tx] = sim[n] * valf[n];
    __syncthreads();
    #pragma unroll
    for (int n = 0; n < NB; ++n) {
        float s = 0.f;
        #pragma unroll
        for (int g = 0; g < 8; ++g) s += psim[g][n][tx];
        sim[n] = s;
    }

    float mx = sim[0];
    #pragma unroll
    for (int n = 1; n < NB; ++n) mx = fmaxf(mx, sim[n]);
    float sum = 0.f;
    #pragma unroll
    for (int n = 0; n < NB; ++n) { sim[n] = __expf(sim[n] - mx); sum += sim[n]; }
    const float inv = 1.f / sum;

    if (ty == 0) {
        #pragma unroll
        for (int n = 0; n < NB; ++n)
            prob[((size_t)b * NB + n) * HW + p] = sim[n] * inv * valf[n];
    }
}

// ---------------------------------------------------------------------------
// PV: ctx(p,c) = sum_n prob[n][p] * V[idx(n,p)][c]; V/ctx (b,p,256) f16.
// ---------------------------------------------------------------------------
__global__ __launch_bounds__(256)
void pv_kernel(const float* __restrict__ prob, const _Float16* __restrict__ valT,
               _Float16* __restrict__ ctxT)
{
    const int tid  = threadIdx.x;
    const int slot = tid & 31;
    const int b    = blockIdx.y;
    const int p    = blockIdx.x * 8 + (tid >> 5);
    const int y    = p >> 6;
    const int xc   = p & 63;

    int idx[NB];
    #pragma unroll
    for (int n = 0; n < NB; ++n) {
        const int d  = (n < 9) ? 1 : (n < 18 ? 2 : 4);
        const int i  = (n / 3) % 3 - 1;
        const int j  = n % 3 - 1;
        idx[n] = min(max(y + i * d, 0), Hh - 1) * Ww + min(max(xc + j * d, 0), Ww - 1);
    }

    const float* pr = prob + (size_t)b * NB * HW + p;
    const _Float16* vb = valT + (size_t)b * HW * 256 + slot * 8;

    float acc[8];
    #pragma unroll
    for (int i = 0; i < 8; ++i) acc[i] = 0.f;

    #pragma unroll
    for (int n = 0; n < NB; ++n) {
        const float w = pr[(size_t)n * HW];
        const f16x8 v8 = *(const f16x8*)(vb + (size_t)idx[n] * 256);
        #pragma unroll
        for (int i = 0; i < 8; ++i) acc[i] = fmaf(w, (float)v8[i], acc[i]);
    }

    f16x8 h;
    #pragma unroll
    for (int i = 0; i < 8; ++i) h[i] = (_Float16)acc[i];
    *(f16x8*)(ctxT + ((size_t)b * HW + p) * 256 + slot * 8) = h;
}

extern "C" void kernel_launch(void* const* d_in, const int* in_sizes, int n_in,
                              void* d_out, int out_size, void* d_ws, size_t ws_size,
                              hipStream_t stream)
{
    (void)in_sizes; (void)n_in; (void)out_size; (void)ws_size;
    const float* x     = (const float*)d_in[0];
    const float* k1_w  = (const float*)d_in[1];
    const float* k1_b  = (const float*)d_in[2];
    const float* k1_g  = (const float*)d_in[3];
    const float* k1_be = (const float*)d_in[4];
    const float* k1_m  = (const float*)d_in[5];
    const float* k1_v  = (const float*)d_in[6];
    const float* k2_w  = (const float*)d_in[7];
    const float* k2_b  = (const float*)d_in[8];
    const float* k2_g  = (const float*)d_in[9];
    const float* k2_be = (const float*)d_in[10];
    const float* k2_m  = (const float*)d_in[11];
    const float* k2_v  = (const float*)d_in[12];
    const float* q1_w  = (const float*)d_in[13];
    const float* q1_b  = (const float*)d_in[14];
    const float* q1_g  = (const float*)d_in[15];
    const float* q1_be = (const float*)d_in[16];
    const float* q1_m  = (const float*)d_in[17];
    const float* q1_v  = (const float*)d_in[18];
    const float* q2_w  = (const float*)d_in[19];
    const float* q2_b  = (const float*)d_in[20];
    const float* q2_g  = (const float*)d_in[21];
    const float* q2_be = (const float*)d_in[22];
    const float* q2_m  = (const float*)d_in[23];
    const float* q2_v  = (const float*)d_in[24];
    const float* v_w   = (const float*)d_in[25];
    const float* v_b   = (const float*)d_in[26];
    const float* w_w   = (const float*)d_in[27];
    const float* w_b   = (const float*)d_in[28];

    _Float16* hw = (_Float16*)d_ws;
    const size_t SX = (size_t)4 * HW * 512;
    const size_t SH = (size_t)4 * HW * 256;
    _Float16* xT    = hw;
    _Float16* wv_h  = xT + SX;
    _Float16* wk1_h = wv_h  + 131072;
    _Float16* wq1_h = wk1_h + 131072;
    _Float16* wk2_h = wq1_h + 131072;
    _Float16* wq2_h = wk2_h + 65536;
    _Float16* ww_h  = wq2_h + 65536;
    _Float16* k1T   = ww_h  + 131072;
    _Float16* q1T   = k1T + SH;
    _Float16* valT  = q1T + SH;
    _Float16* ctxT  = valT + SH;
    _Float16* keyCP = ctxT + SH;
    _Float16* qryCP = keyCP + SH;
    float*    prob  = (float*)(qryCP + SH);

    cvt_w_kernel<<<dim3(64, 6), 256, 0, stream>>>(v_w, k1_w, q1_w, k2_w, q2_w, w_w,
                                                  wv_h, wk1_h, wq1_h, wk2_h, wq2_h, ww_h);
    cvt_x_kernel<<<dim3(64, 16, 4), dim3(64, 4), 0, stream>>>(x, xT);

    GJob jv  = { xT,  wv_h,  v_b,  nullptr, nullptr, nullptr, nullptr, valT,  nullptr };
    GJob jk1 = { xT,  wk1_h, k1_b, k1_g, k1_be, k1_m, k1_v,            k1T,   nullptr };
    GJob jq1 = { xT,  wq1_h, q1_b, q1_g, q1_be, q1_m, q1_v,            q1T,   nullptr };
    GJob jk2 = { k1T, wk2_h, k2_b, k2_g, k2_be, k2_m, k2_v,            keyCP, nullptr };
    GJob jq2 = { q1T, wq2_h, q2_b, q2_g, q2_be, q2_m, q2_v,            qryCP, nullptr };
    GJob jw  = { ctxT, ww_h, w_b,  nullptr, nullptr, nullptr, nullptr, nullptr, (float*)d_out };

    // stage 1: v | k1 | q1  (2 m-blocks each), K=512, out f16 (p,c)
    gemm128<<<dim3(128, 6), 256, 0, stream>>>(jv, jk1, jq1, 2, 4, 512, 256, 0);
    // stage 2: k2 | q2, K=256, out f16 (b,c,p)
    gemm128<<<dim3(128, 4), 256, 0, stream>>>(jk2, jq2, jq2, 2, 4, 256, 256, 1);
    // stage 3a: sim + softmax
    sim_softmax<<<dim3(64, 4), 512, 0, stream>>>(keyCP, qryCP, prob);
    // stage 3b: PV -> ctxT (p,c) f16
    pv_kernel<<<dim3(512, 4), 256, 0, stream>>>(prob, valT, ctxT);
    // stage 4: final conv, K=256, out f32 (b,c,p) -> d_out
    gemm128<<<dim3(128, 4), 256, 0, stream>>>(jw, jw, jw, 4, 4, 256, 512, 2);
}

// Round 8
// 96.653 us; speedup vs baseline: 41.4859x; 1.1045x over previous
//
#include <hip/hip_runtime.h>

#define HW   4096
#define Hh   64
#define Ww   64
#define NB   27
#define EPSBN 1e-5f

typedef _Float16 f16x8 __attribute__((ext_vector_type(8)));
typedef _Float16 f16x4 __attribute__((ext_vector_type(4)));
typedef _Float16 f16x2 __attribute__((ext_vector_type(2)));
typedef float    f32x4 __attribute__((ext_vector_type(4)));

// async global->LDS, 16B per lane; LDS dest = wave-uniform base + lane*16
__device__ __forceinline__ void gld_lds16(const void* g, void* l) {
    __builtin_amdgcn_global_load_lds(
        (const __attribute__((address_space(1))) unsigned int*)g,
        (__attribute__((address_space(3))) unsigned int*)l, 16, 0, 0);
}

// ---------------------------------------------------------------------------
// prep: weights f32 -> f16 (same (O,Cin) layout)
// ---------------------------------------------------------------------------
__global__ __launch_bounds__(256)
void cvt_w_kernel(const float* s0, const float* s1, const float* s2,
                  const float* s3, const float* s4, const float* s5,
                  _Float16* d0, _Float16* d1, _Float16* d2,
                  _Float16* d3, _Float16* d4, _Float16* d5)
{
    const int j = blockIdx.y;
    const float* s = j==0?s0: j==1?s1: j==2?s2: j==3?s3: j==4?s4: s5;
    _Float16*  d = j==0?d0: j==1?d1: j==2?d2: j==3?d3: j==4?d4: d5;
    const int  n = (j==3 || j==4) ? 65536 : 131072;
    const int  i = (blockIdx.x * 256 + threadIdx.x) * 8;
    if (i < n) {
        f16x8 h;
        #pragma unroll
        for (int k = 0; k < 8; ++k) h[k] = (_Float16)s[i + k];
        *(f16x8*)(d + i) = h;
    }
}

// ---------------------------------------------------------------------------
// prep: x (b,c,p) f32 -> xT (b,p,c) f16.
// ---------------------------------------------------------------------------
__global__ __launch_bounds__(256)
void cvt_x_kernel(const float* __restrict__ x, _Float16* __restrict__ xT)
{
    const int tx = threadIdx.x;
    const int ty = threadIdx.y;
    const int p  = blockIdx.x * 64 + tx;
    const int c0 = blockIdx.y * 32 + ty * 8;
    const int b  = blockIdx.z;
    const float* xp = x + ((size_t)b * 512 + c0) * HW + p;
    f16x8 h;
    #pragma unroll
    for (int i = 0; i < 8; ++i) h[i] = (_Float16)xp[(size_t)i * HW];
    *(f16x8*)(xT + ((size_t)b * HW + p) * 512 + c0) = h;
}

// ---------------------------------------------------------------------------
// m97-style GEMM: C[M, 16384] = W[M,K] x inT[16384,K]^T   (both K-contig)
// 128x128 tile, BK=64. 4 waves, each 64x64 (4x4 16x16x32 f16 MFMA frags).
// A+B staged via global_load_lds w=16; LDS XOR-swizzled via pre-swizzled
// global source + same XOR on ds_read side (guide rule #21).
// mode: 0 = f16 out (p,c);  2 = f32 out (b,c,p)
// ---------------------------------------------------------------------------
struct GJob {
    const _Float16* in;   // (16384, K) f16
    const _Float16* w;    // (O, K) f16
    const float* b; const float* g; const float* be; const float* m; const float* v;
    _Float16* oh;
    float*    of;
};

__global__ __launch_bounds__(256)
void gemm128(GJob J0, GJob J1, GJob J2, int nmb0, int nmb01,
             int K, int JO, int mode)
{
    __shared__ _Float16 As[128 * 64];
    __shared__ _Float16 Bs[128 * 64];

    const int tid  = threadIdx.x;
    const int lane = tid & 63;
    const int w    = tid >> 6;
    const int lr   = lane & 15;
    const int lg   = lane >> 4;
    const int wm   = w & 1;
    const int wn   = w >> 1;

    const int bx = blockIdx.x;
    const int nb = (bx & 7) * 16 + (bx >> 3);
    const int mb = blockIdx.y;

    const bool i0 = mb < nmb0;
    const bool i1 = !i0 && mb < nmb01;
#define SELJ(f) (i0 ? J0.f : (i1 ? J1.f : J2.f))
    const _Float16* Jin = SELJ(in);
    const _Float16* Jw  = SELJ(w);
    const float* Jb  = SELJ(b);
    const float* Jg  = SELJ(g);
    const float* Jbe = SELJ(be);
    const float* Jm  = SELJ(m);
    const float* Jv  = SELJ(v);
    _Float16* Joh = SELJ(oh);
    float*    Jof = SELJ(of);
#undef SELJ
    const int obase = (mb - (i0 ? 0 : (i1 ? nmb0 : nmb01))) * 128;

    const int rowS = w * 32 + (lane >> 3);
    const int scol = (((lane & 7) ^ (lane >> 3)) << 3);
    const _Float16* aSrc = Jw  + (size_t)(obase + rowS) * K + scol;
    const _Float16* bSrc = Jin + (size_t)(nb * 128 + rowS) * K + scol;
    char* aDst = (char*)As + w * 4096;
    char* bDst = (char*)Bs + w * 4096;

    f32x4 acc[4][4] = {};

    const int nr = K >> 6;
    for (int rd = 0; rd < nr; ++rd) {
        __syncthreads();
        const int kb = rd * 64;
        #pragma unroll
        for (int j = 0; j < 4; ++j)
            gld_lds16(aSrc + (size_t)j * 8 * K + kb, aDst + j * 1024);
        #pragma unroll
        for (int j = 0; j < 4; ++j)
            gld_lds16(bSrc + (size_t)j * 8 * K + kb, bDst + j * 1024);
        __syncthreads();

        #pragma unroll
        for (int ks = 0; ks < 2; ++ks) {
            const int colx = (ks * 64 + lg * 16) ^ ((lr & 7) << 4);
            f16x8 afr[4], bfr[4];
            #pragma unroll
            for (int t = 0; t < 4; ++t) {
                afr[t] = *(const f16x8*)((const char*)As + (wm * 64 + t * 16 + lr) * 128 + colx);
                bfr[t] = *(const f16x8*)((const char*)Bs + (wn * 64 + t * 16 + lr) * 128 + colx);
            }
            #pragma unroll
            for (int ai = 0; ai < 4; ++ai)
                #pragma unroll
                for (int bj = 0; bj < 4; ++bj)
                    acc[ai][bj] = __builtin_amdgcn_mfma_f32_16x16x32_f16(
                        afr[ai], bfr[bj], acc[ai][bj], 0, 0, 0);
        }
    }

    const int relu = (Jg != nullptr);
    #pragma unroll
    for (int ai = 0; ai < 4; ++ai) {
        const int o4 = obase + wm * 64 + ai * 16 + lg * 4;
        float sc[4], of_[4];
        #pragma unroll
        for (int r = 0; r < 4; ++r) {
            const int o = o4 + r;
            if (Jg) { float s = Jg[o] * rsqrtf(Jv[o] + EPSBN); sc[r] = s; of_[r] = fmaf(Jb[o] - Jm[o], s, Jbe[o]); }
            else    { sc[r] = 1.f; of_[r] = Jb[o]; }
        }
        #pragma unroll
        for (int bj = 0; bj < 4; ++bj) {
            const int pg = nb * 128 + wn * 64 + bj * 16 + lr;
            float vv[4];
            #pragma unroll
            for (int r = 0; r < 4; ++r) {
                float t = fmaf(acc[ai][bj][r], sc[r], of_[r]);
                vv[r] = relu ? fmaxf(t, 0.f) : t;
            }
            if (mode == 0) {
                f16x4 h;
                #pragma unroll
                for (int r = 0; r < 4; ++r) h[r] = (_Float16)vv[r];
                *(f16x4*)(Joh + (size_t)pg * JO + o4) = h;
            } else {
                #pragma unroll
                for (int r = 0; r < 4; ++r)
                    Jof[((size_t)(pg >> 12) * JO + o4 + r) * HW + (pg & 4095)] = vv[r];
            }
        }
    }
}

// ---------------------------------------------------------------------------
// Fused attention: sim + softmax + PV in one pass, all buffers (b,p,256) f16.
// Thread = (pixel, 8-channel slot): 32 consecutive lanes read one full 512B
// neighbor row coalesced (pv-style). Sim partials via fdot2 (f16 pairs, f32
// accum), reduced across the 32 slot-lanes with shfl_xor (masks<=16 stay in
// the pixel's half-wave). Softmax in-register (all lanes redundantly).
// OOB neighbors: clamped idx (reads valid-but-wrong row), zeroed via valf
// AFTER the reduce, prob also zeroed -> matches zero-padded unfold.
// ---------------------------------------------------------------------------
__global__ __launch_bounds__(256)
void attn_fused(const _Float16* __restrict__ keyT, const _Float16* __restrict__ qryT,
                const _Float16* __restrict__ valT, _Float16* __restrict__ ctxT)
{
    const int tid  = threadIdx.x;
    const int slot = tid & 31;
    const int b    = blockIdx.y;
    const int p    = blockIdx.x * 8 + (tid >> 5);
    const int y    = p >> 6;
    const int xc   = p & 63;

    int   idx[NB];
    float valf[NB];
    #pragma unroll
    for (int n = 0; n < NB; ++n) {
        const int d  = (n < 9) ? 1 : (n < 18 ? 2 : 4);
        const int i  = (n / 3) % 3 - 1;
        const int j  = n % 3 - 1;
        const int yy = y + i * d, xx = xc + j * d;
        const bool ok = ((unsigned)yy < (unsigned)Hh) && ((unsigned)xx < (unsigned)Ww);
        idx[n]  = min(max(yy, 0), Hh - 1) * Ww + min(max(xx, 0), Ww - 1);
        valf[n] = ok ? 1.f : 0.f;
    }

    const size_t base = (size_t)b * HW * 256 + slot * 8;
    const f16x8 q8 = *(const f16x8*)(qryT + base + (size_t)p * 256);

    f16x2 qp[4];
    #pragma unroll
    for (int i = 0; i < 4; ++i)
        qp[i] = __builtin_shufflevector(q8, q8, 0, 1);   // placeholder, set below
    qp[0] = __builtin_shufflevector(q8, q8, 0, 1);
    qp[1] = __builtin_shufflevector(q8, q8, 2, 3);
    qp[2] = __builtin_shufflevector(q8, q8, 4, 5);
    qp[3] = __builtin_shufflevector(q8, q8, 6, 7);

    float sim[NB];
    #pragma unroll
    for (int n = 0; n < NB; ++n) {
        const f16x8 k8 = *(const f16x8*)(keyT + base + (size_t)idx[n] * 256);
        float s = 0.f;
        s = __builtin_amdgcn_fdot2(__builtin_shufflevector(k8, k8, 0, 1), qp[0], s, false);
        s = __builtin_amdgcn_fdot2(__builtin_shufflevector(k8, k8, 2, 3), qp[1], s, false);
        s = __builtin_amdgcn_fdot2(__builtin_shufflevector(k8, k8, 4, 5), qp[2], s, false);
        s = __builtin_amdgcn_fdot2(__builtin_shufflevector(k8, k8, 6, 7), qp[3], s, false);
        sim[n] = s;
    }

    // reduce each sim over the 32 slot-lanes (stays within pixel's lane group)
    #pragma unroll
    for (int n = 0; n < NB; ++n) {
        float s = sim[n];
        s += __shfl_xor(s, 1);
        s += __shfl_xor(s, 2);
        s += __shfl_xor(s, 4);
        s += __shfl_xor(s, 8);
        s += __shfl_xor(s, 16);
        sim[n] = s * valf[n];
    }

    float mx = sim[0];
    #pragma unroll
    for (int n = 1; n < NB; ++n) mx = fmaxf(mx, sim[n]);
    float sum = 0.f;
    #pragma unroll
    for (int n = 0; n < NB; ++n) { sim[n] = __expf(sim[n] - mx); sum += sim[n]; }
    const float inv = 1.f / sum;
    #pragma unroll
    for (int n = 0; n < NB; ++n) sim[n] = sim[n] * inv * valf[n];

    float acc[8];
    #pragma unroll
    for (int i = 0; i < 8; ++i) acc[i] = 0.f;
    #pragma unroll
    for (int n = 0; n < NB; ++n) {
        const f16x8 v8 = *(const f16x8*)(valT + base + (size_t)idx[n] * 256);
        const float w = sim[n];
        #pragma unroll
        for (int i = 0; i < 8; ++i) acc[i] = fmaf(w, (float)v8[i], acc[i]);
    }

    f16x8 h;
    #pragma unroll
    for (int i = 0; i < 8; ++i) h[i] = (_Float16)acc[i];
    *(f16x8*)(ctxT + base + (size_t)p * 256) = h;
}

extern "C" void kernel_launch(void* const* d_in, const int* in_sizes, int n_in,
                              void* d_out, int out_size, void* d_ws, size_t ws_size,
                              hipStream_t stream)
{
    (void)in_sizes; (void)n_in; (void)out_size; (void)ws_size;
    const float* x     = (const float*)d_in[0];
    const float* k1_w  = (const float*)d_in[1];
    const float* k1_b  = (const float*)d_in[2];
    const float* k1_g  = (const float*)d_in[3];
    const float* k1_be = (const float*)d_in[4];
    const float* k1_m  = (const float*)d_in[5];
    const float* k1_v  = (const float*)d_in[6];
    const float* k2_w  = (const float*)d_in[7];
    const float* k2_b  = (const float*)d_in[8];
    const float* k2_g  = (const float*)d_in[9];
    const float* k2_be = (const float*)d_in[10];
    const float* k2_m  = (const float*)d_in[11];
    const float* k2_v  = (const float*)d_in[12];
    const float* q1_w  = (const float*)d_in[13];
    const float* q1_b  = (const float*)d_in[14];
    const float* q1_g  = (const float*)d_in[15];
    const float* q1_be = (const float*)d_in[16];
    const float* q1_m  = (const float*)d_in[17];
    const float* q1_v  = (const float*)d_in[18];
    const float* q2_w  = (const float*)d_in[19];
    const float* q2_b  = (const float*)d_in[20];
    const float* q2_g  = (const float*)d_in[21];
    const float* q2_be = (const float*)d_in[22];
    const float* q2_m  = (const float*)d_in[23];
    const float* q2_v  = (const float*)d_in[24];
    const float* v_w   = (const float*)d_in[25];
    const float* v_b   = (const float*)d_in[26];
    const float* w_w   = (const float*)d_in[27];
    const float* w_b   = (const float*)d_in[28];

    _Float16* hw = (_Float16*)d_ws;
    const size_t SX = (size_t)4 * HW * 512;
    const size_t SH = (size_t)4 * HW * 256;
    _Float16* xT    = hw;
    _Float16* wv_h  = xT + SX;
    _Float16* wk1_h = wv_h  + 131072;
    _Float16* wq1_h = wk1_h + 131072;
    _Float16* wk2_h = wq1_h + 131072;
    _Float16* wq2_h = wk2_h + 65536;
    _Float16* ww_h  = wq2_h + 65536;
    _Float16* k1T   = ww_h  + 131072;
    _Float16* q1T   = k1T + SH;
    _Float16* valT  = q1T + SH;
    _Float16* ctxT  = valT + SH;
    _Float16* keyPC = ctxT + SH;
    _Float16* qryPC = keyPC + SH;

    cvt_w_kernel<<<dim3(64, 6), 256, 0, stream>>>(v_w, k1_w, q1_w, k2_w, q2_w, w_w,
                                                  wv_h, wk1_h, wq1_h, wk2_h, wq2_h, ww_h);
    cvt_x_kernel<<<dim3(64, 16, 4), dim3(64, 4), 0, stream>>>(x, xT);

    GJob jv  = { xT,  wv_h,  v_b,  nullptr, nullptr, nullptr, nullptr, valT,  nullptr };
    GJob jk1 = { xT,  wk1_h, k1_b, k1_g, k1_be, k1_m, k1_v,            k1T,   nullptr };
    GJob jq1 = { xT,  wq1_h, q1_b, q1_g, q1_be, q1_m, q1_v,            q1T,   nullptr };
    GJob jk2 = { k1T, wk2_h, k2_b, k2_g, k2_be, k2_m, k2_v,            keyPC, nullptr };
    GJob jq2 = { q1T, wq2_h, q2_b, q2_g, q2_be, q2_m, q2_v,            qryPC, nullptr };
    GJob jw  = { ctxT, ww_h, w_b,  nullptr, nullptr, nullptr, nullptr, nullptr, (float*)d_out };

    // stage 1: v | k1 | q1  (2 m-blocks each), K=512, out f16 (p,c)
    gemm128<<<dim3(128, 6), 256, 0, stream>>>(jv, jk1, jq1, 2, 4, 512, 256, 0);
    // stage 2: k2 | q2, K=256, out f16 (p,c)
    gemm128<<<dim3(128, 4), 256, 0, stream>>>(jk2, jq2, jq2, 2, 4, 256, 256, 0);
    // stage 3: fused sim+softmax+PV -> ctxT (p,c) f16
    attn_fused<<<dim3(512, 4), 256, 0, stream>>>(keyPC, qryPC, valT, ctxT);
    // stage 4: final conv, K=256, out f32 (b,c,p) -> d_out
    gemm128<<<dim3(128, 4), 256, 0, stream>>>(jw, jw, jw, 4, 4, 256, 512, 2);
}